// Round 3
// baseline (102.024 us; speedup 1.0000x reference)
//
#include <hip/hip_runtime.h>
#include <cstdint>

// ModConv: y[b,o,l] = sum_{i,k} bw[b,o,i,k] * x[b,i,l+k-1],
//   bw = conv_w * s[b,i] * demod[b,o],  s = t@mod_w^T + mod_b + 1,
//   demod = rsqrt(sum_{i,k} (conv_w*s)^2 + 1e-8)
// BM=64 so LDS = A(49152) + XT(32768) = 81920 exactly -> 2 blocks/CU.
// XT holds exactly the tile's 128 columns (no halo): edge taps are zeroed
// per-lane in the MFMA loop and re-added by a per-block epilogue that reads
// the modulated weights back from LDS. 4 o-tile blocks of one (b,chunk)
// share an XCD for x L2 reuse.

namespace {
constexpr int NB = 16, NI = 128, NO = 256, NK = 3, NT = 256, NL = 8192;
constexpr int BM = 64, BN = 128, TPB = 8;     // block: 64 o x (8*128) l
constexpr int A_BYTES = NK * BM * 256;        // 49152
constexpr int XT_OFF  = A_BYTES;
constexpr int SMEM_BYTES = XT_OFF + 128 * 256;   // 81920 == 160KB/2
}

typedef __attribute__((ext_vector_type(8))) short bf16x8;
typedef __attribute__((ext_vector_type(4))) float f32x4;

__device__ __forceinline__ uint32_t f2bf(float f) {
    uint32_t u = __builtin_bit_cast(uint32_t, f);
    return (u + 0x7fffu + ((u >> 16) & 1u)) >> 16;   // RNE
}

__launch_bounds__(512, 4)
__global__ void modconv(const float* __restrict__ x,
                        const float* __restrict__ tvec,
                        const float* __restrict__ conv_w,
                        const float* __restrict__ mod_w,
                        const float* __restrict__ mod_b,
                        float* __restrict__ out) {
    __shared__ __align__(16) char smem[SMEM_BYTES];
    float* s_sh = reinterpret_cast<float*>(smem + XT_OFF);        // prologue
    float* d_sh = reinterpret_cast<float*>(smem + XT_OFF + 512);  // prologue
    float* u_sh = reinterpret_cast<float*>(smem + XT_OFF);        // epilogue

    const int tid = threadIdx.x;

    // ---- XCD grouping: 4 o-tiles of one (b,chunk) share bid&7
    const int bid  = blockIdx.x;
    const int slot = bid >> 3;                   // [0,64)
    const int m    = slot & 3;                   // o-tile
    const int g    = (bid & 7) + 8 * (slot >> 2);  // [0,128)
    const int b     = g >> 3;
    const int chunk = g & 7;
    const int o0    = m * BM;

    const float* xb = x + (size_t)b * NI * NL;
    float* outb     = out + ((size_t)b * NO + o0) * NL;
    const int C     = chunk * (TPB * BN);

    // ---- staged X loads: 128 rows (=cols C+t*128 .. +127), no halo, no guards
    float xr[4][8];
    const int lrow = tid & 31;       // consecutive lanes -> consecutive l
    const int ig   = tid >> 5;       // 16 groups x 8 i

    auto issue_loads = [&](int lt0) {
        #pragma unroll
        for (int p = 0; p < 4; ++p) {
            const float* px = xb + (size_t)(ig * 8) * NL + (lt0 + p * 32 + lrow);
            #pragma unroll
            for (int n = 0; n < 8; ++n) xr[p][n] = px[(size_t)n * NL];
        }
    };
    auto write_stage = [&]() {
        #pragma unroll
        for (int p = 0; p < 4; ++p) {
            const int r = p * 32 + lrow;
            uint32_t d0 = f2bf(xr[p][0]) | (f2bf(xr[p][1]) << 16);
            uint32_t d1 = f2bf(xr[p][2]) | (f2bf(xr[p][3]) << 16);
            uint32_t d2 = f2bf(xr[p][4]) | (f2bf(xr[p][5]) << 16);
            uint32_t d3 = f2bf(xr[p][6]) | (f2bf(xr[p][7]) << 16);
            *reinterpret_cast<uint4*>(
                smem + XT_OFF + r * 256 + ((ig * 16) ^ ((r & 15) << 4))) =
                make_uint4(d0, d1, d2, d3);
        }
    };

    issue_loads(C);   // tile-0 x flies under the whole prologue

    // ---- phase 1: s[i] = dot(t[b], mod_w[i]) + mod_b[i] + 1   (4 thr/i)
    {
        const int i = tid >> 2, q = tid & 3;
        const float* tp = tvec + b * NT + q * 64;
        const float* mp = mod_w + i * NT + q * 64;
        float acc = 0.f;
        #pragma unroll 8
        for (int j = 0; j < 64; ++j) acc = fmaf(tp[j], mp[j], acc);
        acc += __shfl_xor(acc, 1);
        acc += __shfl_xor(acc, 2);
        if (q == 0) s_sh[i] = acc + mod_b[i] + 1.0f;
    }
    __syncthreads();

    // ---- phase 2: demod[o] (8 thr/o, 64 o)
    {
        const int o_l = tid >> 3, q = tid & 7;
        const float* cw = conv_w + (size_t)(o0 + o_l) * (NI * NK) + q * 16 * NK;
        float sum = 0.f;
        #pragma unroll 4
        for (int ii = 0; ii < 16; ++ii) {
            float s  = s_sh[q * 16 + ii];
            float w0 = cw[ii * 3 + 0], w1 = cw[ii * 3 + 1], w2 = cw[ii * 3 + 2];
            sum = fmaf(s * s, w0 * w0 + w1 * w1 + w2 * w2, sum);
        }
        sum += __shfl_xor(sum, 1);
        sum += __shfl_xor(sum, 2);
        sum += __shfl_xor(sum, 4);
        if (q == 0) d_sh[o_l] = rsqrtf(sum + 1e-8f);
    }
    __syncthreads();

    // ---- phase 3: A = bw tile -> LDS bf16, byte(k,o,i)=k*16384+o*256+((i*2)^((o&15)<<4))
    for (int idx = tid; idx < BM * (NI / 2); idx += 512) {
        const int i2 = idx & 63, o = idx >> 6;
        const float* cw = conv_w + ((size_t)(o0 + o) * NI + i2 * 2) * NK;
        const float dm = d_sh[o];
        const float mA = s_sh[i2 * 2] * dm, mB = s_sh[i2 * 2 + 1] * dm;
        const int base = o * 256, sw = ((i2 * 4) ^ ((o & 15) << 4));
        #pragma unroll
        for (int k = 0; k < NK; ++k) {
            uint32_t v = f2bf(cw[k] * mA) | (f2bf(cw[k + NK] * mB) << 16);
            *reinterpret_cast<uint32_t*>(smem + k * 16384 + base + sw) = v;
        }
    }
    __syncthreads();   // s/d consumed, A visible

    const int lane = tid & 63;
    const int wid  = tid >> 6;
    const int wm   = wid >> 2, wn = wid & 3;    // 2x4 waves, 32x32 out each
    const int l16  = lane & 15, lg4 = lane >> 4;
    const bf16x8 zf = {0, 0, 0, 0, 0, 0, 0, 0};

    for (int tile = 0; tile < TPB; ++tile) {
        const int l0 = C + tile * BN;
        write_stage();                 // XT <- tile (drains this tile's loads)
        __syncthreads();
        if (tile + 1 < TPB) issue_loads(l0 + BN);   // next tile under MFMA

        f32x4 acc[2][2];
        const f32x4 zero = {0.f, 0.f, 0.f, 0.f};
        #pragma unroll
        for (int fm = 0; fm < 2; ++fm)
            #pragma unroll
            for (int fn = 0; fn < 2; ++fn) acc[fm][fn] = zero;

        #pragma unroll
        for (int k = 0; k < NK; ++k) {
            #pragma unroll
            for (int kc = 0; kc < 4; ++kc) {
                const int cb = kc * 64 + lg4 * 16;
                bf16x8 af[2], bfr[2];
                #pragma unroll
                for (int fm = 0; fm < 2; ++fm) {
                    const int o = wm * 32 + fm * 16 + l16;
                    af[fm] = *reinterpret_cast<const bf16x8*>(
                        smem + k * 16384 + o * 256 + (cb ^ ((o & 15) << 4)));
                }
                #pragma unroll
                for (int fn = 0; fn < 2; ++fn) {
                    int r = wn * 32 + fn * 16 + l16 + k - 1;
                    r = r < 0 ? 0 : (r > 127 ? 127 : r);
                    bfr[fn] = *reinterpret_cast<const bf16x8*>(
                        smem + XT_OFF + r * 256 + (cb ^ ((r & 15) << 4)));
                }
                if (k == 0 && wn == 0) bfr[0] = (l16 == 0)  ? zf : bfr[0];
                if (k == 2 && wn == 3) bfr[1] = (l16 == 15) ? zf : bfr[1];
                #pragma unroll
                for (int fm = 0; fm < 2; ++fm)
                    #pragma unroll
                    for (int fn = 0; fn < 2; ++fn)
                        acc[fm][fn] = __builtin_amdgcn_mfma_f32_16x16x32_bf16(
                            af[fm], bfr[fn], acc[fm][fn], 0, 0, 0);
            }
        }

        // ---- write C: row = wm*32+fm*16+lg4*4+j, col = l0+wn*32+fn*16+l16
        #pragma unroll
        for (int fm = 0; fm < 2; ++fm) {
            #pragma unroll
            for (int fn = 0; fn < 2; ++fn) {
                const int og = wm * 32 + fm * 16 + lg4 * 4;
                const int lg = l0 + wn * 32 + fn * 16 + l16;
                #pragma unroll
                for (int j = 0; j < 4; ++j)
                    __builtin_nontemporal_store(
                        acc[fm][fn][j], &outb[(size_t)(og + j) * NL + lg]);
            }
        }
        __syncthreads();               // all waves done reading XT tile
    }

    // ---- epilogue: re-add the 16 zeroed boundary taps of this block's span
    //      term e: t=e>>1, side=e&1; side0: y[:,C+128t]   += A[0]·x[:,C+128t-1]
    //                                side1: y[:,C+128t+127]+= A[2]·x[:,C+128t+128]
    #pragma unroll 1
    for (int it = 0; it < 4; ++it) {
        {   // stage u[4][128] = x columns
            const int el = tid >> 7, i = tid & 127, e = it * 4 + el;
            const int t = e >> 1, side = e & 1;
            const int src = side == 0 ? C + 128 * t - 1 : C + 128 * t + 128;
            u_sh[el * 128 + i] =
                (src >= 0 && src < NL) ? xb[(size_t)i * NL + src] : 0.f;
        }
        __syncthreads();
        {   // accumulate: thread = (term, o, half)
            const int el = tid >> 7, e = it * 4 + el;
            const int t = e >> 1, side = e & 1;
            const int o = (tid >> 1) & 63, half = tid & 1;
            const int ktap = side == 0 ? 0 : 2;
            const int src  = side == 0 ? C + 128 * t - 1 : C + 128 * t + 128;
            const int dst  = side == 0 ? C + 128 * t     : C + 128 * t + 127;
            float acc = 0.f;
            #pragma unroll 8
            for (int ii = 0; ii < 64; ++ii) {
                const int i = half * 64 + ii;
                uint32_t aw = *reinterpret_cast<const uint16_t*>(
                    smem + ktap * 16384 + o * 256 + ((i * 2) ^ ((o & 15) << 4)));
                acc = fmaf(__builtin_bit_cast(float, aw << 16),
                           u_sh[el * 128 + i], acc);
            }
            acc += __shfl_xor(acc, 1);
            if (half == 0 && src >= 0 && src < NL) {
                float* p = &outb[(size_t)o * NL + dst];
                *p = *p + acc;
            }
        }
        __syncthreads();
    }
}

extern "C" void kernel_launch(void* const* d_in, const int* in_sizes, int n_in,
                              void* d_out, int out_size, void* d_ws, size_t ws_size,
                              hipStream_t stream) {
    const float* x      = (const float*)d_in[0];
    const float* t      = (const float*)d_in[1];
    const float* conv_w = (const float*)d_in[2];
    const float* mod_w  = (const float*)d_in[3];
    const float* mod_b  = (const float*)d_in[4];

    // 4 o-tiles x 8 chunks x 16 b = 512 blocks, 2 per CU
    modconv<<<dim3(512), dim3(512), 0, stream>>>(x, t, conv_w, mod_w, mod_b,
                                                 (float*)d_out);
}